// Round 1
// baseline (1551.289 us; speedup 1.0000x reference)
//
#include <hip/hip_runtime.h>
#include <hip/hip_bf16.h>

// Problem constants
#define B_  2
#define T_  4
#define N_  512
#define D_  768
#define H_  12
#define DH_ 64
// derived
#define ROWS_ (B_ * T_ * N_)          // 4096
#define NBATCH_ (B_ * H_ * T_)        // 96
#define SLAB_QKV_ (N_ * DH_)          // 32768 floats per (b,h,t) slab of q/k/v
#define SLAB_S_ (N_ * N_)             // 262144 floats per (b,h,t) slab of scores
#define TOTAL_SPK_ (B_ * H_ * T_ * N_ * N_)  // 25165824

// GEMM tile config: 64x64 C-tile per 256-thread block, K-step 16, 4x4 micro-tile
#define BM 64
#define BN 64
#define BK 16
#define LDP (BM + 4)   // padded LDS leading dim: stride 68 floats keeps 16B align, <=2-way bank conflict

// ---------------------------------------------------------------------------
// Kernel 1: fused QKV projection.  y = x @ W^T  (NT GEMM, M=4096, N=768, K=768)
// scatter-write into [B, H, T, N, Dh] layout so later batched GEMMs get
// contiguous (b,h,t) slabs.
// ---------------------------------------------------------------------------
__global__ __launch_bounds__(256) void proj_gemm(
    const float* __restrict__ x,
    const float* __restrict__ wq, const float* __restrict__ wk, const float* __restrict__ wv,
    float* __restrict__ qo, float* __restrict__ ko, float* __restrict__ vo)
{
    const int zw = blockIdx.z;  // 0=q, 1=k, 2=v (uniform per block)
    const float* __restrict__ w = (zw == 0) ? wq : (zw == 1) ? wk : wv;
    float* __restrict__ dst = (zw == 0) ? qo : (zw == 1) ? ko : vo;
    const int m0 = blockIdx.x * BM;
    const int n0 = blockIdx.y * BN;

    __shared__ float As[BK][LDP];
    __shared__ float Bs[BK][LDP];

    const int tid = threadIdx.x;
    const int tx = tid & 15, ty = tid >> 4;
    const int lr = tid >> 2;            // 0..63 row within tile
    const int lc = (tid & 3) << 2;      // 0,4,8,12 k within chunk

    float acc[4][4] = {};

    for (int k0 = 0; k0 < D_; k0 += BK) {
        float4 a4 = *reinterpret_cast<const float4*>(&x[(size_t)(m0 + lr) * D_ + k0 + lc]);
        float4 b4 = *reinterpret_cast<const float4*>(&w[(size_t)(n0 + lr) * D_ + k0 + lc]);
        __syncthreads();
        As[lc + 0][lr] = a4.x; As[lc + 1][lr] = a4.y; As[lc + 2][lr] = a4.z; As[lc + 3][lr] = a4.w;
        Bs[lc + 0][lr] = b4.x; Bs[lc + 1][lr] = b4.y; Bs[lc + 2][lr] = b4.z; Bs[lc + 3][lr] = b4.w;
        __syncthreads();
        #pragma unroll
        for (int kk = 0; kk < BK; ++kk) {
            float4 av = *reinterpret_cast<const float4*>(&As[kk][ty << 2]);
            float4 bv = *reinterpret_cast<const float4*>(&Bs[kk][tx << 2]);
            float a[4] = {av.x, av.y, av.z, av.w};
            float b[4] = {bv.x, bv.y, bv.z, bv.w};
            #pragma unroll
            for (int i = 0; i < 4; ++i)
                #pragma unroll
                for (int j = 0; j < 4; ++j)
                    acc[i][j] += a[i] * b[j];
        }
    }

    // scatter: row=(b,t,n), col=h*64+dh  ->  dst[b][h][t][n][dh]
    const int col0 = n0 + (tx << 2);
    const int h = col0 >> 6, dh = col0 & 63;   // 4 consecutive cols stay in one head
    #pragma unroll
    for (int i = 0; i < 4; ++i) {
        const int row = m0 + (ty << 2) + i;
        const int b = row >> 11;          // row / (T*N) = /2048
        const int t = (row >> 9) & 3;
        const int n = row & 511;
        float4 val = {acc[i][0], acc[i][1], acc[i][2], acc[i][3]};
        *reinterpret_cast<float4*>(
            &dst[((((size_t)(b * H_ + h) * T_ + t) * N_ + n) << 6) + dh]) = val;
    }
}

// ---------------------------------------------------------------------------
// Kernel 2: batched scores.  S = (q_slab @ k_slab^T) * scale   (NT, M=N=512, K=64)
// batch z = ((b*H+h)*T + t), 96 batches
// ---------------------------------------------------------------------------
__global__ __launch_bounds__(256) void score_gemm(
    const float* __restrict__ q, const float* __restrict__ k, float* __restrict__ S)
{
    const int batch = blockIdx.z;
    const float* __restrict__ A  = q + (size_t)batch * SLAB_QKV_;
    const float* __restrict__ Bp = k + (size_t)batch * SLAB_QKV_;
    float* __restrict__ C = S + (size_t)batch * SLAB_S_;
    const int m0 = blockIdx.x * BM;
    const int n0 = blockIdx.y * BN;

    __shared__ float As[BK][LDP];
    __shared__ float Bs[BK][LDP];

    const int tid = threadIdx.x;
    const int tx = tid & 15, ty = tid >> 4;
    const int lr = tid >> 2;
    const int lc = (tid & 3) << 2;

    float acc[4][4] = {};

    for (int k0 = 0; k0 < DH_; k0 += BK) {
        float4 a4 = *reinterpret_cast<const float4*>(&A [(size_t)(m0 + lr) * DH_ + k0 + lc]);
        float4 b4 = *reinterpret_cast<const float4*>(&Bp[(size_t)(n0 + lr) * DH_ + k0 + lc]);
        __syncthreads();
        As[lc + 0][lr] = a4.x; As[lc + 1][lr] = a4.y; As[lc + 2][lr] = a4.z; As[lc + 3][lr] = a4.w;
        Bs[lc + 0][lr] = b4.x; Bs[lc + 1][lr] = b4.y; Bs[lc + 2][lr] = b4.z; Bs[lc + 3][lr] = b4.w;
        __syncthreads();
        #pragma unroll
        for (int kk = 0; kk < BK; ++kk) {
            float4 av = *reinterpret_cast<const float4*>(&As[kk][ty << 2]);
            float4 bv = *reinterpret_cast<const float4*>(&Bs[kk][tx << 2]);
            float a[4] = {av.x, av.y, av.z, av.w};
            float b[4] = {bv.x, bv.y, bv.z, bv.w};
            #pragma unroll
            for (int i = 0; i < 4; ++i)
                #pragma unroll
                for (int j = 0; j < 4; ++j)
                    acc[i][j] += a[i] * b[j];
        }
    }

    const float scale = 0.125f;  // Dh^-0.5 = 1/8
    #pragma unroll
    for (int i = 0; i < 4; ++i) {
        const int row = m0 + (ty << 2) + i;
        float4 val = {acc[i][0] * scale, acc[i][1] * scale, acc[i][2] * scale, acc[i][3] * scale};
        *reinterpret_cast<float4*>(&C[(size_t)row * N_ + n0 + (tx << 2)]) = val;
    }
}

// ---------------------------------------------------------------------------
// Kernel 3: LIF recurrence over t (in-place S -> spikes) + global spike count
// one thread per (b,h,n,m); 6291456 threads
// ---------------------------------------------------------------------------
__global__ __launch_bounds__(256) void lif_kernel(
    float* __restrict__ S, unsigned int* __restrict__ cnt)
{
    const size_t idx = (size_t)blockIdx.x * 256 + threadIdx.x;   // exact, no bounds check
    const int m  = (int)(idx & 511);
    const int n  = (int)((idx >> 9) & 511);
    const int bh = (int)(idx >> 18);                              // 0..23
    float* p = S + (size_t)bh * (T_ * SLAB_S_) + (size_t)n * N_ + m;

    const float beta = 0.95122942450071400f;  // exp(-1/20)
    float mem = 0.0f;
    int c = 0;
    #pragma unroll
    for (int t = 0; t < T_; ++t) {
        const float s = p[(size_t)t * SLAB_S_];
        mem = beta * mem + s;
        const float spk = (mem >= 0.5f) ? 1.0f : 0.0f;
        mem -= spk * 0.5f;
        p[(size_t)t * SLAB_S_] = spk;
        c += (int)spk;
    }
    // wave-64 reduce, one atomic per wave
    #pragma unroll
    for (int off = 32; off > 0; off >>= 1) c += __shfl_down(c, off);
    if ((threadIdx.x & 63) == 0) atomicAdd(cnt, (unsigned int)c);
}

// ---------------------------------------------------------------------------
// Kernel 4: batched PV.  pre = spk_slab @ v_slab   (NN, M=512, N=64, K=512)
// scatter-write into [B, T, N, D] so the WO GEMM is a plain row-major NT GEMM.
// ---------------------------------------------------------------------------
__global__ __launch_bounds__(256) void pv_gemm(
    const float* __restrict__ S, const float* __restrict__ v, float* __restrict__ pre)
{
    const int batch = blockIdx.z;
    const float* __restrict__ A  = S + (size_t)batch * SLAB_S_;    // [512 x 512]
    const float* __restrict__ Bp = v + (size_t)batch * SLAB_QKV_;  // [512 x 64]
    const int m0 = blockIdx.x * BM;

    __shared__ float As[BK][LDP];
    __shared__ float Bs[BK][LDP];

    const int tid = threadIdx.x;
    const int tx = tid & 15, ty = tid >> 4;
    const int lr = tid >> 2;
    const int lc = (tid & 3) << 2;
    const int kr = tid >> 4;            // 0..15 k-row for B (NN) load
    const int kc = (tid & 15) << 2;     // 0..60 n-col

    float acc[4][4] = {};

    for (int k0 = 0; k0 < N_; k0 += BK) {
        float4 a4 = *reinterpret_cast<const float4*>(&A [(size_t)(m0 + lr) * N_ + k0 + lc]);
        float4 b4 = *reinterpret_cast<const float4*>(&Bp[(size_t)(k0 + kr) * DH_ + kc]);
        __syncthreads();
        As[lc + 0][lr] = a4.x; As[lc + 1][lr] = a4.y; As[lc + 2][lr] = a4.z; As[lc + 3][lr] = a4.w;
        *reinterpret_cast<float4*>(&Bs[kr][kc]) = b4;
        __syncthreads();
        #pragma unroll
        for (int kk = 0; kk < BK; ++kk) {
            float4 av = *reinterpret_cast<const float4*>(&As[kk][ty << 2]);
            float4 bv = *reinterpret_cast<const float4*>(&Bs[kk][tx << 2]);
            float a[4] = {av.x, av.y, av.z, av.w};
            float b[4] = {bv.x, bv.y, bv.z, bv.w};
            #pragma unroll
            for (int i = 0; i < 4; ++i)
                #pragma unroll
                for (int j = 0; j < 4; ++j)
                    acc[i][j] += a[i] * b[j];
        }
    }

    // batch = ((b*H+h)*T + t)
    const int b = batch / (H_ * T_);
    const int h = (batch / T_) % H_;
    const int t = batch % T_;
    const int dh = tx << 2;
    #pragma unroll
    for (int i = 0; i < 4; ++i) {
        const int n = m0 + (ty << 2) + i;
        float4 val = {acc[i][0], acc[i][1], acc[i][2], acc[i][3]};
        *reinterpret_cast<float4*>(
            &pre[((size_t)((b * T_ + t) * N_ + n)) * D_ + h * DH_ + dh]) = val;
    }
}

// ---------------------------------------------------------------------------
// Kernel 5: output projection.  out = pre @ wo^T  (NT, M=4096, N=768, K=768)
// ---------------------------------------------------------------------------
__global__ __launch_bounds__(256) void wo_gemm(
    const float* __restrict__ A, const float* __restrict__ w, float* __restrict__ C)
{
    const int m0 = blockIdx.x * BM;
    const int n0 = blockIdx.y * BN;

    __shared__ float As[BK][LDP];
    __shared__ float Bs[BK][LDP];

    const int tid = threadIdx.x;
    const int tx = tid & 15, ty = tid >> 4;
    const int lr = tid >> 2;
    const int lc = (tid & 3) << 2;

    float acc[4][4] = {};

    for (int k0 = 0; k0 < D_; k0 += BK) {
        float4 a4 = *reinterpret_cast<const float4*>(&A[(size_t)(m0 + lr) * D_ + k0 + lc]);
        float4 b4 = *reinterpret_cast<const float4*>(&w[(size_t)(n0 + lr) * D_ + k0 + lc]);
        __syncthreads();
        As[lc + 0][lr] = a4.x; As[lc + 1][lr] = a4.y; As[lc + 2][lr] = a4.z; As[lc + 3][lr] = a4.w;
        Bs[lc + 0][lr] = b4.x; Bs[lc + 1][lr] = b4.y; Bs[lc + 2][lr] = b4.z; Bs[lc + 3][lr] = b4.w;
        __syncthreads();
        #pragma unroll
        for (int kk = 0; kk < BK; ++kk) {
            float4 av = *reinterpret_cast<const float4*>(&As[kk][ty << 2]);
            float4 bv = *reinterpret_cast<const float4*>(&Bs[kk][tx << 2]);
            float a[4] = {av.x, av.y, av.z, av.w};
            float b[4] = {bv.x, bv.y, bv.z, bv.w};
            #pragma unroll
            for (int i = 0; i < 4; ++i)
                #pragma unroll
                for (int j = 0; j < 4; ++j)
                    acc[i][j] += a[i] * b[j];
        }
    }

    #pragma unroll
    for (int i = 0; i < 4; ++i) {
        const int row = m0 + (ty << 2) + i;
        float4 val = {acc[i][0], acc[i][1], acc[i][2], acc[i][3]};
        *reinterpret_cast<float4*>(&C[(size_t)row * D_ + n0 + (tx << 2)]) = val;
    }
}

// ---------------------------------------------------------------------------
// Kernel 6: attn_rate = spike_count / 25165824
// ---------------------------------------------------------------------------
__global__ void rate_kernel(const unsigned int* __restrict__ cnt, float* __restrict__ out)
{
    out[0] = (float)(*cnt) * (1.0f / (float)TOTAL_SPK_);
}

// ---------------------------------------------------------------------------
extern "C" void kernel_launch(void* const* d_in, const int* in_sizes, int n_in,
                              void* d_out, int out_size, void* d_ws, size_t ws_size,
                              hipStream_t stream)
{
    const float* x  = (const float*)d_in[0];
    const float* wq = (const float*)d_in[1];
    const float* wk = (const float*)d_in[2];
    const float* wv = (const float*)d_in[3];
    const float* wo = (const float*)d_in[4];
    float* out = (float*)d_out;

    // workspace layout (floats): q,k,v [B,H,T,N,Dh] | S/spk [B,H,T,N,N] | pre [B,T,N,D] | count
    float* ws  = (float*)d_ws;
    float* q   = ws;
    float* k   = q + (size_t)B_ * H_ * T_ * N_ * DH_;   // +3145728
    float* v   = k + (size_t)B_ * H_ * T_ * N_ * DH_;
    float* S   = v + (size_t)B_ * H_ * T_ * N_ * DH_;
    float* pre = S + (size_t)TOTAL_SPK_;                // +25165824
    unsigned int* cnt = (unsigned int*)(pre + (size_t)B_ * T_ * N_ * D_);
    // total ws use: ~151 MB

    proj_gemm <<<dim3(ROWS_ / BM, D_ / BN, 3), 256, 0, stream>>>(x, wq, wk, wv, q, k, v);
    score_gemm<<<dim3(N_ / BM, N_ / BN, NBATCH_), 256, 0, stream>>>(q, k, S);
    hipMemsetAsync(cnt, 0, sizeof(unsigned int), stream);
    lif_kernel<<<dim3((B_ * H_ * N_ * N_) / 256), 256, 0, stream>>>(S, cnt);
    pv_gemm   <<<dim3(N_ / BM, 1, NBATCH_), 256, 0, stream>>>(S, v, pre);
    wo_gemm   <<<dim3(ROWS_ / BM, D_ / BN), 256, 0, stream>>>(pre, wo, out);
    rate_kernel<<<1, 1, 0, stream>>>(cnt, out + (size_t)B_ * T_ * N_ * D_);
}

// Round 2
// 438.271 us; speedup vs baseline: 3.5396x; 3.5396x over previous
//
#include <hip/hip_runtime.h>
#include <hip/hip_bf16.h>

// Problem constants
#define B_  2
#define T_  4
#define N_  512
#define D_  768
#define H_  12
#define DH_ 64
// derived
#define ROWS_ (B_ * T_ * N_)          // 4096
#define NBATCH_ (B_ * H_ * T_)        // 96
#define SLAB_QKV_ (N_ * DH_)          // 32768 floats per (b,h,t) slab of q/k/v
#define SLAB_S_ (N_ * N_)             // 262144 floats per (b,h,t) slab of scores
#define TOTAL_SPK_ (B_ * H_ * T_ * N_ * N_)  // 25165824
#define NBLK_SCORE_ (8 * 8 * 24)      // score_lif_gemm grid = 1536 blocks

// GEMM tile config: 64x64 C-tile per 256-thread block, K-step 16, 4x4 micro-tile
#define BM 64
#define BN 64
#define BK 16
#define LDP (BM + 4)   // padded LDS leading dim: stride 68 floats keeps 16B align, <=2-way bank conflict

// ---------------------------------------------------------------------------
// Kernel 1: fused QKV projection.  y = x @ W^T  (NT GEMM, M=4096, N=768, K=768)
// scatter-write into [B, H, T, N, Dh] layout so later batched GEMMs get
// contiguous (b,h,t) slabs.
// ---------------------------------------------------------------------------
__global__ __launch_bounds__(256) void proj_gemm(
    const float* __restrict__ x,
    const float* __restrict__ wq, const float* __restrict__ wk, const float* __restrict__ wv,
    float* __restrict__ qo, float* __restrict__ ko, float* __restrict__ vo)
{
    const int zw = blockIdx.z;  // 0=q, 1=k, 2=v (uniform per block)
    const float* __restrict__ w = (zw == 0) ? wq : (zw == 1) ? wk : wv;
    float* __restrict__ dst = (zw == 0) ? qo : (zw == 1) ? ko : vo;
    const int m0 = blockIdx.x * BM;
    const int n0 = blockIdx.y * BN;

    __shared__ float As[BK][LDP];
    __shared__ float Bs[BK][LDP];

    const int tid = threadIdx.x;
    const int tx = tid & 15, ty = tid >> 4;
    const int lr = tid >> 2;            // 0..63 row within tile
    const int lc = (tid & 3) << 2;      // 0,4,8,12 k within chunk

    float acc[4][4] = {};

    for (int k0 = 0; k0 < D_; k0 += BK) {
        float4 a4 = *reinterpret_cast<const float4*>(&x[(size_t)(m0 + lr) * D_ + k0 + lc]);
        float4 b4 = *reinterpret_cast<const float4*>(&w[(size_t)(n0 + lr) * D_ + k0 + lc]);
        __syncthreads();
        As[lc + 0][lr] = a4.x; As[lc + 1][lr] = a4.y; As[lc + 2][lr] = a4.z; As[lc + 3][lr] = a4.w;
        Bs[lc + 0][lr] = b4.x; Bs[lc + 1][lr] = b4.y; Bs[lc + 2][lr] = b4.z; Bs[lc + 3][lr] = b4.w;
        __syncthreads();
        #pragma unroll
        for (int kk = 0; kk < BK; ++kk) {
            float4 av = *reinterpret_cast<const float4*>(&As[kk][ty << 2]);
            float4 bv = *reinterpret_cast<const float4*>(&Bs[kk][tx << 2]);
            float a[4] = {av.x, av.y, av.z, av.w};
            float b[4] = {bv.x, bv.y, bv.z, bv.w};
            #pragma unroll
            for (int i = 0; i < 4; ++i)
                #pragma unroll
                for (int j = 0; j < 4; ++j)
                    acc[i][j] += a[i] * b[j];
        }
    }

    // scatter: row=(b,t,n), col=h*64+dh  ->  dst[b][h][t][n][dh]
    const int col0 = n0 + (tx << 2);
    const int h = col0 >> 6, dh = col0 & 63;   // 4 consecutive cols stay in one head
    #pragma unroll
    for (int i = 0; i < 4; ++i) {
        const int row = m0 + (ty << 2) + i;
        const int b = row >> 11;          // row / (T*N) = /2048
        const int t = (row >> 9) & 3;
        const int n = row & 511;
        float4 val = {acc[i][0], acc[i][1], acc[i][2], acc[i][3]};
        *reinterpret_cast<float4*>(
            &dst[((((size_t)(b * H_ + h) * T_ + t) * N_ + n) << 6) + dh]) = val;
    }
}

// ---------------------------------------------------------------------------
// Kernel 2: fused scores + LIF.  For one (b,h) and one 64x64 (n,m)-tile, loop
// t=0..3: acc = q_t @ k_t^T * scale (K=64), carry LIF membrane in registers,
// write spikes. Eliminates the score round-trip AND the atomic-serialized
// lif_kernel (R1: 1123 us of single-address atomics at ~45 ns each).
// Spike count: block LDS reduce -> per-block slot (NO atomics).
// ---------------------------------------------------------------------------
__global__ __launch_bounds__(256) void score_lif_gemm(
    const float* __restrict__ q, const float* __restrict__ k,
    float* __restrict__ spk, unsigned int* __restrict__ cnt)
{
    const int bh = blockIdx.z;          // 0..23  (b*H + h)
    const int m0 = blockIdx.x * BM;     // query-row tile base
    const int n0 = blockIdx.y * BN;     // key-col tile base

    __shared__ float As[BK][LDP];
    __shared__ float Bs[BK][LDP];
    __shared__ int red4[4];

    const int tid = threadIdx.x;
    const int tx = tid & 15, ty = tid >> 4;
    const int lr = tid >> 2;
    const int lc = (tid & 3) << 2;

    const float beta = 0.95122942450071400f;  // exp(-1/20)
    const float scale = 0.125f;               // Dh^-0.5

    float mem[4][4] = {};
    int c = 0;

    for (int t = 0; t < T_; ++t) {
        const float* __restrict__ A  = q + (size_t)(bh * T_ + t) * SLAB_QKV_;
        const float* __restrict__ Bp = k + (size_t)(bh * T_ + t) * SLAB_QKV_;
        float acc[4][4] = {};

        for (int k0 = 0; k0 < DH_; k0 += BK) {
            float4 a4 = *reinterpret_cast<const float4*>(&A [(size_t)(m0 + lr) * DH_ + k0 + lc]);
            float4 b4 = *reinterpret_cast<const float4*>(&Bp[(size_t)(n0 + lr) * DH_ + k0 + lc]);
            __syncthreads();
            As[lc + 0][lr] = a4.x; As[lc + 1][lr] = a4.y; As[lc + 2][lr] = a4.z; As[lc + 3][lr] = a4.w;
            Bs[lc + 0][lr] = b4.x; Bs[lc + 1][lr] = b4.y; Bs[lc + 2][lr] = b4.z; Bs[lc + 3][lr] = b4.w;
            __syncthreads();
            #pragma unroll
            for (int kk = 0; kk < BK; ++kk) {
                float4 av = *reinterpret_cast<const float4*>(&As[kk][ty << 2]);
                float4 bv = *reinterpret_cast<const float4*>(&Bs[kk][tx << 2]);
                float a[4] = {av.x, av.y, av.z, av.w};
                float b[4] = {bv.x, bv.y, bv.z, bv.w};
                #pragma unroll
                for (int i = 0; i < 4; ++i)
                    #pragma unroll
                    for (int j = 0; j < 4; ++j)
                        acc[i][j] += a[i] * b[j];
            }
        }

        // LIF step for this t, entirely in registers
        float* __restrict__ C = spk + (size_t)(bh * T_ + t) * SLAB_S_;
        #pragma unroll
        for (int i = 0; i < 4; ++i) {
            float4 val;
            float* vp = &val.x;
            #pragma unroll
            for (int j = 0; j < 4; ++j) {
                float mm = beta * mem[i][j] + acc[i][j] * scale;
                float sp = (mm >= 0.5f) ? 1.0f : 0.0f;
                mem[i][j] = mm - sp * 0.5f;
                vp[j] = sp;
                c += (int)sp;
            }
            const int row = m0 + (ty << 2) + i;   // query index n
            *reinterpret_cast<float4*>(&C[(size_t)row * N_ + n0 + (tx << 2)]) = val;
        }
    }

    // spike-count reduction: wave shuffle -> 4 slots -> thread 0 -> per-block slot
    #pragma unroll
    for (int off = 32; off > 0; off >>= 1) c += __shfl_down(c, off);
    if ((tid & 63) == 0) red4[tid >> 6] = c;
    __syncthreads();
    if (tid == 0) {
        cnt[(blockIdx.z * gridDim.y + blockIdx.y) * gridDim.x + blockIdx.x] =
            (unsigned int)(red4[0] + red4[1] + red4[2] + red4[3]);
    }
}

// ---------------------------------------------------------------------------
// Kernel 3: batched PV.  pre = spk_slab @ v_slab   (NN, M=512, N=64, K=512)
// scatter-write into [B, T, N, D] so the WO GEMM is a plain row-major NT GEMM.
// ---------------------------------------------------------------------------
__global__ __launch_bounds__(256) void pv_gemm(
    const float* __restrict__ S, const float* __restrict__ v, float* __restrict__ pre)
{
    const int batch = blockIdx.z;
    const float* __restrict__ A  = S + (size_t)batch * SLAB_S_;    // [512 x 512]
    const float* __restrict__ Bp = v + (size_t)batch * SLAB_QKV_;  // [512 x 64]
    const int m0 = blockIdx.x * BM;

    __shared__ float As[BK][LDP];
    __shared__ float Bs[BK][LDP];

    const int tid = threadIdx.x;
    const int tx = tid & 15, ty = tid >> 4;
    const int lr = tid >> 2;
    const int lc = (tid & 3) << 2;
    const int kr = tid >> 4;            // 0..15 k-row for B (NN) load
    const int kc = (tid & 15) << 2;     // 0..60 n-col

    float acc[4][4] = {};

    for (int k0 = 0; k0 < N_; k0 += BK) {
        float4 a4 = *reinterpret_cast<const float4*>(&A [(size_t)(m0 + lr) * N_ + k0 + lc]);
        float4 b4 = *reinterpret_cast<const float4*>(&Bp[(size_t)(k0 + kr) * DH_ + kc]);
        __syncthreads();
        As[lc + 0][lr] = a4.x; As[lc + 1][lr] = a4.y; As[lc + 2][lr] = a4.z; As[lc + 3][lr] = a4.w;
        *reinterpret_cast<float4*>(&Bs[kr][kc]) = b4;
        __syncthreads();
        #pragma unroll
        for (int kk = 0; kk < BK; ++kk) {
            float4 av = *reinterpret_cast<const float4*>(&As[kk][ty << 2]);
            float4 bv = *reinterpret_cast<const float4*>(&Bs[kk][tx << 2]);
            float a[4] = {av.x, av.y, av.z, av.w};
            float b[4] = {bv.x, bv.y, bv.z, bv.w};
            #pragma unroll
            for (int i = 0; i < 4; ++i)
                #pragma unroll
                for (int j = 0; j < 4; ++j)
                    acc[i][j] += a[i] * b[j];
        }
    }

    // batch = ((b*H+h)*T + t)
    const int b = batch / (H_ * T_);
    const int h = (batch / T_) % H_;
    const int t = batch % T_;
    const int dh = tx << 2;
    #pragma unroll
    for (int i = 0; i < 4; ++i) {
        const int n = m0 + (ty << 2) + i;
        float4 val = {acc[i][0], acc[i][1], acc[i][2], acc[i][3]};
        *reinterpret_cast<float4*>(
            &pre[((size_t)((b * T_ + t) * N_ + n)) * D_ + h * DH_ + dh]) = val;
    }
}

// ---------------------------------------------------------------------------
// Kernel 4: output projection.  out = pre @ wo^T  (NT, M=4096, N=768, K=768)
// ---------------------------------------------------------------------------
__global__ __launch_bounds__(256) void wo_gemm(
    const float* __restrict__ A, const float* __restrict__ w, float* __restrict__ C)
{
    const int m0 = blockIdx.x * BM;
    const int n0 = blockIdx.y * BN;

    __shared__ float As[BK][LDP];
    __shared__ float Bs[BK][LDP];

    const int tid = threadIdx.x;
    const int tx = tid & 15, ty = tid >> 4;
    const int lr = tid >> 2;
    const int lc = (tid & 3) << 2;

    float acc[4][4] = {};

    for (int k0 = 0; k0 < D_; k0 += BK) {
        float4 a4 = *reinterpret_cast<const float4*>(&A[(size_t)(m0 + lr) * D_ + k0 + lc]);
        float4 b4 = *reinterpret_cast<const float4*>(&w[(size_t)(n0 + lr) * D_ + k0 + lc]);
        __syncthreads();
        As[lc + 0][lr] = a4.x; As[lc + 1][lr] = a4.y; As[lc + 2][lr] = a4.z; As[lc + 3][lr] = a4.w;
        Bs[lc + 0][lr] = b4.x; Bs[lc + 1][lr] = b4.y; Bs[lc + 2][lr] = b4.z; Bs[lc + 3][lr] = b4.w;
        __syncthreads();
        #pragma unroll
        for (int kk = 0; kk < BK; ++kk) {
            float4 av = *reinterpret_cast<const float4*>(&As[kk][ty << 2]);
            float4 bv = *reinterpret_cast<const float4*>(&Bs[kk][tx << 2]);
            float a[4] = {av.x, av.y, av.z, av.w};
            float b[4] = {bv.x, bv.y, bv.z, bv.w};
            #pragma unroll
            for (int i = 0; i < 4; ++i)
                #pragma unroll
                for (int j = 0; j < 4; ++j)
                    acc[i][j] += a[i] * b[j];
        }
    }

    #pragma unroll
    for (int i = 0; i < 4; ++i) {
        const int row = m0 + (ty << 2) + i;
        float4 val = {acc[i][0], acc[i][1], acc[i][2], acc[i][3]};
        *reinterpret_cast<float4*>(&C[(size_t)row * D_ + n0 + (tx << 2)]) = val;
    }
}

// ---------------------------------------------------------------------------
// Kernel 5: attn_rate = sum(per-block spike counts) / 25165824
// single block, 256 threads, no atomics anywhere
// ---------------------------------------------------------------------------
__global__ __launch_bounds__(256) void rate_kernel(
    const unsigned int* __restrict__ cnt, float* __restrict__ out)
{
    __shared__ unsigned int red4[4];
    const int tid = threadIdx.x;
    unsigned int c = 0;
    for (int i = tid; i < NBLK_SCORE_; i += 256) c += cnt[i];
    #pragma unroll
    for (int off = 32; off > 0; off >>= 1) c += __shfl_down(c, off);
    if ((tid & 63) == 0) red4[tid >> 6] = c;
    __syncthreads();
    if (tid == 0)
        out[0] = (float)(red4[0] + red4[1] + red4[2] + red4[3]) * (1.0f / (float)TOTAL_SPK_);
}

// ---------------------------------------------------------------------------
extern "C" void kernel_launch(void* const* d_in, const int* in_sizes, int n_in,
                              void* d_out, int out_size, void* d_ws, size_t ws_size,
                              hipStream_t stream)
{
    const float* x  = (const float*)d_in[0];
    const float* wq = (const float*)d_in[1];
    const float* wk = (const float*)d_in[2];
    const float* wv = (const float*)d_in[3];
    const float* wo = (const float*)d_in[4];
    float* out = (float*)d_out;

    // workspace layout (floats): q,k,v [B,H,T,N,Dh] | spk [B,H,T,N,N] | pre [B,T,N,D] | cnt[1536]
    float* ws  = (float*)d_ws;
    float* q   = ws;
    float* k   = q + (size_t)B_ * H_ * T_ * N_ * DH_;   // +3145728
    float* v   = k + (size_t)B_ * H_ * T_ * N_ * DH_;
    float* spk = v + (size_t)B_ * H_ * T_ * N_ * DH_;
    float* pre = spk + (size_t)TOTAL_SPK_;              // +25165824
    unsigned int* cnt = (unsigned int*)(pre + (size_t)B_ * T_ * N_ * D_);
    // total ws use: ~151 MB

    proj_gemm     <<<dim3(ROWS_ / BM, D_ / BN, 3), 256, 0, stream>>>(x, wq, wk, wv, q, k, v);
    score_lif_gemm<<<dim3(N_ / BM, N_ / BN, B_ * H_), 256, 0, stream>>>(q, k, spk, cnt);
    pv_gemm       <<<dim3(N_ / BM, 1, NBATCH_), 256, 0, stream>>>(spk, v, pre);
    wo_gemm       <<<dim3(ROWS_ / BM, D_ / BN), 256, 0, stream>>>(pre, wo, out);
    rate_kernel   <<<1, 256, 0, stream>>>(cnt, out + (size_t)B_ * T_ * N_ * D_);
}

// Round 3
// 170.487 us; speedup vs baseline: 9.0992x; 2.5707x over previous
//
#include <hip/hip_runtime.h>
#include <hip/hip_bf16.h>

// Problem constants
#define B_  2
#define T_  4
#define N_  512
#define D_  768
#define H_  12
#define DH_ 64
#define TOTAL_SPK_ (B_ * H_ * T_ * N_ * N_)  // 25165824
#define NBLK_SCORE_ 384                       // 4*4*24

typedef unsigned short u16;
typedef __attribute__((ext_vector_type(8))) __bf16 bf16x8;
typedef __attribute__((ext_vector_type(4))) float f32x4;
typedef __attribute__((ext_vector_type(4))) u16 u16x4;
typedef __attribute__((ext_vector_type(8))) u16 u16x8;
typedef __attribute__((address_space(1))) const unsigned int glds_src;
typedef __attribute__((address_space(3))) unsigned int glds_dst;

__device__ __forceinline__ u16 f2bf(float f) {
    unsigned int u = __builtin_bit_cast(unsigned int, f);
    u += 0x7fffu + ((u >> 16) & 1u);          // RNE
    return (u16)(u >> 16);
}

// ---------------------------------------------------------------------------
// Stage nrows rows (multiple of 8; lrow0 multiple of 8) of a [*][64]-bf16 LDS
// tile (128 B rows) from row-major global (stride gld elems, k0 elem offset).
// global_load_lds writes linearly (wave base + lane*16); the XOR swizzle
// (byte ^= (row&7)<<4) is applied by PRE-SWIZZLING the per-lane global source
// column (rule #21: linear dest + inverse-swz source + swz on read).
// Since lrow0 % 8 == 0, (row&7) == lane>>3, so src col = ((lane&7)^(lane>>3))<<4.
// ---------------------------------------------------------------------------
__device__ __forceinline__ void stage64(u16* lds, const u16* g, int gld,
                                        int lrow0, int nrows, int grow0, int k0, int lane)
{
    const int sub = lane >> 3;                              // row within 8-row instr
    const int csrc = (((lane & 7) ^ sub) << 4);             // pre-swizzled src byte col
    #pragma unroll
    for (int j = 0; j < nrows; j += 8) {
        const u16* src = g + (size_t)(grow0 + j + sub) * gld + k0 + (csrc >> 1);
        __builtin_amdgcn_global_load_lds((glds_src*)src,
                                         (glds_dst*)(lds + (lrow0 + j) * 64),
                                         16, 0, 0);
    }
}

// Read one 16x32 A/B fragment (8 bf16/lane) from a swizzled [*][64] tile.
// lane l: row = rowbase + (l&15), k = kelem + (l>>4)*8 .. +8
__device__ __forceinline__ bf16x8 ldfrag(const u16* lds, int rowbase, int kelem, int lane)
{
    const int r = rowbase + (lane & 15);
    const int cb = (((kelem + ((lane >> 4) << 3)) << 1)) ^ ((r & 7) << 4);
    return *reinterpret_cast<const bf16x8*>(
        reinterpret_cast<const char*>(lds) + (size_t)r * 128 + cb);
}

#define MFMA(a, b, c) __builtin_amdgcn_mfma_f32_16x16x32_bf16((a), (b), (c), 0, 0, 0)

// ---------------------------------------------------------------------------
// Kernel 0: cast fp32 -> bf16 (x and the four weight matrices)
// ---------------------------------------------------------------------------
__global__ __launch_bounds__(256) void cast_all(
    const float* __restrict__ x,  const float* __restrict__ wq, const float* __restrict__ wk,
    const float* __restrict__ wv, const float* __restrict__ wo,
    u16* __restrict__ xb, u16* __restrict__ wqb, u16* __restrict__ wkb,
    u16* __restrict__ wvb, u16* __restrict__ wob)
{
    const int z = blockIdx.y;
    const float* s; u16* d; int n4;
    switch (z) {
        case 0: s = x;  d = xb;  n4 = (B_*T_*N_*D_) / 4; break;   // 786432
        case 1: s = wq; d = wqb; n4 = (D_*D_) / 4; break;         // 147456
        case 2: s = wk; d = wkb; n4 = (D_*D_) / 4; break;
        case 3: s = wv; d = wvb; n4 = (D_*D_) / 4; break;
        default: s = wo; d = wob; n4 = (D_*D_) / 4; break;
    }
    const int i = blockIdx.x * 256 + threadIdx.x;
    if (i < n4) {
        float4 v = reinterpret_cast<const float4*>(s)[i];
        u16x4 o = { f2bf(v.x), f2bf(v.y), f2bf(v.z), f2bf(v.w) };
        reinterpret_cast<u16x4*>(d)[i] = o;
    }
}

// ---------------------------------------------------------------------------
// Kernel 1: QKV projection, bf16 MFMA NT-GEMM.  y = x @ W^T, M=4096 N=768 K=768
// z picks weight. q,k stored [bh][t][n][64] bf16; v stored TRANSPOSED
// vT[bh][t][dh][n] so the PV GEMM is also NT with K contiguous.
// ---------------------------------------------------------------------------
__global__ __launch_bounds__(256) void proj_mfma(
    const u16* __restrict__ xb,
    const u16* __restrict__ wqb, const u16* __restrict__ wkb, const u16* __restrict__ wvb,
    u16* __restrict__ q, u16* __restrict__ k, u16* __restrict__ vT)
{
    const int z = blockIdx.z;
    const u16* __restrict__ w = (z == 0) ? wqb : (z == 1) ? wkb : wvb;
    const int m0 = blockIdx.x * 128;
    const int n0 = blockIdx.y * 128;
    __shared__ u16 As[128 * 64];
    __shared__ u16 Bs[128 * 64];
    const int tid = threadIdx.x, lane = tid & 63, wid = tid >> 6;
    const int wr = wid >> 1, wc = wid & 1;

    f32x4 acc[4][4];
    #pragma unroll
    for (int i = 0; i < 4; ++i)
        #pragma unroll
        for (int j = 0; j < 4; ++j) acc[i][j] = f32x4{0.f, 0.f, 0.f, 0.f};

    for (int k0 = 0; k0 < D_; k0 += 64) {
        __syncthreads();
        stage64(As, xb, D_, wid * 32, 32, m0 + wid * 32, k0, lane);
        stage64(Bs, w,  D_, wid * 32, 32, n0 + wid * 32, k0, lane);
        __syncthreads();
        bf16x8 af[4][2], bfr[4][2];
        #pragma unroll
        for (int mi = 0; mi < 4; ++mi) {
            af[mi][0] = ldfrag(As, wr * 64 + mi * 16, 0, lane);
            af[mi][1] = ldfrag(As, wr * 64 + mi * 16, 32, lane);
        }
        #pragma unroll
        for (int ni = 0; ni < 4; ++ni) {
            bfr[ni][0] = ldfrag(Bs, wc * 64 + ni * 16, 0, lane);
            bfr[ni][1] = ldfrag(Bs, wc * 64 + ni * 16, 32, lane);
        }
        #pragma unroll
        for (int kk = 0; kk < 2; ++kk)
            #pragma unroll
            for (int mi = 0; mi < 4; ++mi)
                #pragma unroll
                for (int ni = 0; ni < 4; ++ni)
                    acc[mi][ni] = MFMA(af[mi][kk], bfr[ni][kk], acc[mi][ni]);
    }

    // C/D layout: col = lane&15, row = (lane>>4)*4 + reg   [m89/m91 verified]
    if (z < 2) {
        u16* __restrict__ dst = (z == 0) ? q : k;
        #pragma unroll
        for (int mi = 0; mi < 4; ++mi)
            #pragma unroll
            for (int ni = 0; ni < 4; ++ni) {
                const int col = n0 + wc * 64 + ni * 16 + (lane & 15);
                const int h = col >> 6, dh = col & 63;
                const int row0 = m0 + wr * 64 + mi * 16 + ((lane >> 4) << 2);
                const int b = row0 >> 11, t = (row0 >> 9) & 3, n = row0 & 511;
                u16* p = dst + (size_t)(((b * H_ + h) * T_ + t) * N_ + n) * 64 + dh;
                f32x4 a = acc[mi][ni];
                p[0] = f2bf(a[0]); p[64] = f2bf(a[1]); p[128] = f2bf(a[2]); p[192] = f2bf(a[3]);
            }
    } else {
        #pragma unroll
        for (int mi = 0; mi < 4; ++mi)
            #pragma unroll
            for (int ni = 0; ni < 4; ++ni) {
                const int col = n0 + wc * 64 + ni * 16 + (lane & 15);
                const int h = col >> 6, dh = col & 63;
                const int row0 = m0 + wr * 64 + mi * 16 + ((lane >> 4) << 2);
                const int b = row0 >> 11, t = (row0 >> 9) & 3, n = row0 & 511;
                f32x4 a = acc[mi][ni];
                u16x4 o = { f2bf(a[0]), f2bf(a[1]), f2bf(a[2]), f2bf(a[3]) };
                *reinterpret_cast<u16x4*>(
                    vT + (size_t)(((b * H_ + h) * T_ + t) * 64 + dh) * N_ + n) = o;
            }
    }
}

// ---------------------------------------------------------------------------
// Kernel 2: fused scores + LIF, bf16 MFMA.  Per (bh, 128x128 (n,m)-tile):
// loop t: S = q_t @ k_t^T * 0.125 (K=64), LIF membrane in registers, spikes
// -> LDS (reusing the staging buffers) -> coalesced bf16 global write.
// ---------------------------------------------------------------------------
__global__ __launch_bounds__(256) void score_lif_mfma(
    const u16* __restrict__ q, const u16* __restrict__ k,
    u16* __restrict__ spk, unsigned int* __restrict__ cnt)
{
    const int bh = blockIdx.z;
    const int n0 = blockIdx.x * 128;    // query rows
    const int mb0 = blockIdx.y * 128;   // key cols
    __shared__ u16 SM[128 * 128];       // 32 KB: staging (As|Bs) then spike tile
    u16* As = SM;
    u16* Bs = SM + 8192;
    __shared__ int red4[4];
    const int tid = threadIdx.x, lane = tid & 63, wid = tid >> 6;
    const int wr = wid >> 1, wc = wid & 1;

    const float beta = 0.95122942450071400f;  // exp(-1/20)
    f32x4 mem[4][4];
    #pragma unroll
    for (int i = 0; i < 4; ++i)
        #pragma unroll
        for (int j = 0; j < 4; ++j) mem[i][j] = f32x4{0.f, 0.f, 0.f, 0.f};
    int c = 0;

    for (int t = 0; t < T_; ++t) {
        const u16* qs = q + (size_t)(bh * T_ + t) * (N_ * 64);
        const u16* ks = k + (size_t)(bh * T_ + t) * (N_ * 64);
        __syncthreads();
        stage64(As, qs, 64, wid * 32, 32, n0 + wid * 32, 0, lane);
        stage64(Bs, ks, 64, wid * 32, 32, mb0 + wid * 32, 0, lane);
        __syncthreads();

        f32x4 acc[4][4];
        #pragma unroll
        for (int i = 0; i < 4; ++i)
            #pragma unroll
            for (int j = 0; j < 4; ++j) acc[i][j] = f32x4{0.f, 0.f, 0.f, 0.f};
        bf16x8 af[4][2], bfr[4][2];
        #pragma unroll
        for (int mi = 0; mi < 4; ++mi) {
            af[mi][0] = ldfrag(As, wr * 64 + mi * 16, 0, lane);
            af[mi][1] = ldfrag(As, wr * 64 + mi * 16, 32, lane);
        }
        #pragma unroll
        for (int ni = 0; ni < 4; ++ni) {
            bfr[ni][0] = ldfrag(Bs, wc * 64 + ni * 16, 0, lane);
            bfr[ni][1] = ldfrag(Bs, wc * 64 + ni * 16, 32, lane);
        }
        #pragma unroll
        for (int kk = 0; kk < 2; ++kk)
            #pragma unroll
            for (int mi = 0; mi < 4; ++mi)
                #pragma unroll
                for (int ni = 0; ni < 4; ++ni)
                    acc[mi][ni] = MFMA(af[mi][kk], bfr[ni][kk], acc[mi][ni]);

        __syncthreads();   // all LDS reads done before spike tile overwrites SM

        // LIF update (registers) + spike tile into LDS as bf16
        #pragma unroll
        for (int mi = 0; mi < 4; ++mi)
            #pragma unroll
            for (int ni = 0; ni < 4; ++ni) {
                const int lcol = wc * 64 + ni * 16 + (lane & 15);
                const int lrow0 = wr * 64 + mi * 16 + ((lane >> 4) << 2);
                f32x4 a = acc[mi][ni];
                #pragma unroll
                for (int r = 0; r < 4; ++r) {
                    float mm = beta * mem[mi][ni][r] + a[r] * 0.125f;
                    const bool sp = (mm >= 0.5f);
                    mem[mi][ni][r] = mm - (sp ? 0.5f : 0.0f);
                    SM[(lrow0 + r) * 128 + lcol] = sp ? (u16)0x3F80u : (u16)0u;
                    c += sp ? 1 : 0;
                }
            }
        __syncthreads();

        // coalesced copy-out: 16 lanes cover one 256 B row segment
        u16* gb = spk + ((size_t)(bh * T_ + t) << 18) + (size_t)n0 * N_ + mb0;
        #pragma unroll
        for (int p = 0; p < 8; ++p) {
            const int row = p * 16 + (tid >> 4);
            const int cc = (tid & 15) * 8;
            *reinterpret_cast<u16x8*>(gb + (size_t)row * N_ + cc) =
                *reinterpret_cast<const u16x8*>(SM + row * 128 + cc);
        }
    }

    #pragma unroll
    for (int off = 32; off > 0; off >>= 1) c += __shfl_down(c, off);
    if ((tid & 63) == 0) red4[tid >> 6] = c;
    __syncthreads();
    if (tid == 0)
        cnt[(blockIdx.z * 4 + blockIdx.y) * 4 + blockIdx.x] =
            (unsigned int)(red4[0] + red4[1] + red4[2] + red4[3]);
}

// ---------------------------------------------------------------------------
// Kernel 3: PV, bf16 MFMA NT-GEMM.  pre = spk @ v.  A = spk[n][m] (K=m=512),
// B = vT[dh][m].  Tile 256x64, 4 waves stacked in M. Output bf16 [b,t,n][D].
// ---------------------------------------------------------------------------
__global__ __launch_bounds__(256) void pv_mfma(
    const u16* __restrict__ spk, const u16* __restrict__ vT, u16* __restrict__ pre)
{
    const int batch = blockIdx.z;                 // bh*4 + t
    const int m0 = blockIdx.x * 256;              // n rows
    const u16* A  = spk + ((size_t)batch << 18);
    const u16* Bv = vT + (size_t)batch * (64 * N_);
    __shared__ u16 As[256 * 64];
    __shared__ u16 Bs[64 * 64];
    const int tid = threadIdx.x, lane = tid & 63, wid = tid >> 6;

    f32x4 acc[4][4];
    #pragma unroll
    for (int i = 0; i < 4; ++i)
        #pragma unroll
        for (int j = 0; j < 4; ++j) acc[i][j] = f32x4{0.f, 0.f, 0.f, 0.f};

    for (int k0 = 0; k0 < N_; k0 += 64) {
        __syncthreads();
        stage64(As, A,  N_, wid * 64, 64, m0 + wid * 64, k0, lane);
        stage64(Bs, Bv, N_, wid * 16, 16, wid * 16,      k0, lane);
        __syncthreads();
        bf16x8 af[4][2], bfr[4][2];
        #pragma unroll
        for (int mi = 0; mi < 4; ++mi) {
            af[mi][0] = ldfrag(As, wid * 64 + mi * 16, 0, lane);
            af[mi][1] = ldfrag(As, wid * 64 + mi * 16, 32, lane);
        }
        #pragma unroll
        for (int ni = 0; ni < 4; ++ni) {
            bfr[ni][0] = ldfrag(Bs, ni * 16, 0, lane);
            bfr[ni][1] = ldfrag(Bs, ni * 16, 32, lane);
        }
        #pragma unroll
        for (int kk = 0; kk < 2; ++kk)
            #pragma unroll
            for (int mi = 0; mi < 4; ++mi)
                #pragma unroll
                for (int ni = 0; ni < 4; ++ni)
                    acc[mi][ni] = MFMA(af[mi][kk], bfr[ni][kk], acc[mi][ni]);
    }

    const int bh = batch >> 2, t = batch & 3;
    const int b = bh / H_, h = bh % H_;
    #pragma unroll
    for (int mi = 0; mi < 4; ++mi)
        #pragma unroll
        for (int ni = 0; ni < 4; ++ni) {
            const int dh = ni * 16 + (lane & 15);
            const int n = m0 + wid * 64 + mi * 16 + ((lane >> 4) << 2);
            f32x4 a = acc[mi][ni];
            u16* p = pre + (size_t)((b * T_ + t) * N_ + n) * D_ + h * 64 + dh;
            p[0] = f2bf(a[0]); p[D_] = f2bf(a[1]); p[2 * D_] = f2bf(a[2]); p[3 * D_] = f2bf(a[3]);
        }
}

// ---------------------------------------------------------------------------
// Kernel 4: output projection, bf16 MFMA NT-GEMM. out = pre @ wo^T (fp32 out)
// ---------------------------------------------------------------------------
__global__ __launch_bounds__(256) void wo_mfma(
    const u16* __restrict__ pre, const u16* __restrict__ wob, float* __restrict__ out)
{
    const int m0 = blockIdx.x * 128;
    const int n0 = blockIdx.y * 128;
    __shared__ u16 As[128 * 64];
    __shared__ u16 Bs[128 * 64];
    const int tid = threadIdx.x, lane = tid & 63, wid = tid >> 6;
    const int wr = wid >> 1, wc = wid & 1;

    f32x4 acc[4][4];
    #pragma unroll
    for (int i = 0; i < 4; ++i)
        #pragma unroll
        for (int j = 0; j < 4; ++j) acc[i][j] = f32x4{0.f, 0.f, 0.f, 0.f};

    for (int k0 = 0; k0 < D_; k0 += 64) {
        __syncthreads();
        stage64(As, pre, D_, wid * 32, 32, m0 + wid * 32, k0, lane);
        stage64(Bs, wob, D_, wid * 32, 32, n0 + wid * 32, k0, lane);
        __syncthreads();
        bf16x8 af[4][2], bfr[4][2];
        #pragma unroll
        for (int mi = 0; mi < 4; ++mi) {
            af[mi][0] = ldfrag(As, wr * 64 + mi * 16, 0, lane);
            af[mi][1] = ldfrag(As, wr * 64 + mi * 16, 32, lane);
        }
        #pragma unroll
        for (int ni = 0; ni < 4; ++ni) {
            bfr[ni][0] = ldfrag(Bs, wc * 64 + ni * 16, 0, lane);
            bfr[ni][1] = ldfrag(Bs, wc * 64 + ni * 16, 32, lane);
        }
        #pragma unroll
        for (int kk = 0; kk < 2; ++kk)
            #pragma unroll
            for (int mi = 0; mi < 4; ++mi)
                #pragma unroll
                for (int ni = 0; ni < 4; ++ni)
                    acc[mi][ni] = MFMA(af[mi][kk], bfr[ni][kk], acc[mi][ni]);
    }

    #pragma unroll
    for (int mi = 0; mi < 4; ++mi)
        #pragma unroll
        for (int ni = 0; ni < 4; ++ni) {
            const int col = n0 + wc * 64 + ni * 16 + (lane & 15);
            const int row0 = m0 + wr * 64 + mi * 16 + ((lane >> 4) << 2);
            f32x4 a = acc[mi][ni];
            float* p = out + (size_t)row0 * D_ + col;
            p[0] = a[0]; p[D_] = a[1]; p[2 * D_] = a[2]; p[3 * D_] = a[3];
        }
}

// ---------------------------------------------------------------------------
// Kernel 5: attn_rate = sum(per-block counts) / 25165824   (no atomics)
// ---------------------------------------------------------------------------
__global__ __launch_bounds__(256) void rate_kernel(
    const unsigned int* __restrict__ cnt, float* __restrict__ out)
{
    __shared__ unsigned int red4[4];
    const int tid = threadIdx.x;
    unsigned int c = 0;
    for (int i = tid; i < NBLK_SCORE_; i += 256) c += cnt[i];
    #pragma unroll
    for (int off = 32; off > 0; off >>= 1) c += __shfl_down(c, off);
    if ((tid & 63) == 0) red4[tid >> 6] = c;
    __syncthreads();
    if (tid == 0) {
        double total = (double)red4[0] + red4[1] + red4[2] + red4[3];
        out[0] = (float)(total / (double)TOTAL_SPK_);
    }
}

// ---------------------------------------------------------------------------
extern "C" void kernel_launch(void* const* d_in, const int* in_sizes, int n_in,
                              void* d_out, int out_size, void* d_ws, size_t ws_size,
                              hipStream_t stream)
{
    const float* x  = (const float*)d_in[0];
    const float* wq = (const float*)d_in[1];
    const float* wk = (const float*)d_in[2];
    const float* wv = (const float*)d_in[3];
    const float* wo = (const float*)d_in[4];
    float* out = (float*)d_out;

    // workspace (u16 units): xb | wqb wkb wvb wob | q k vT | spk | pre | cnt
    u16* xb  = (u16*)d_ws;                          // 3145728
    u16* wqb = xb + (size_t)B_ * T_ * N_ * D_;      // 589824 each
    u16* wkb = wqb + D_ * D_;
    u16* wvb = wkb + D_ * D_;
    u16* wob = wvb + D_ * D_;
    u16* q   = wob + D_ * D_;                       // 3145728 each
    u16* k   = q + (size_t)B_ * H_ * T_ * N_ * 64;
    u16* vT  = k + (size_t)B_ * H_ * T_ * N_ * 64;
    u16* spk = vT + (size_t)B_ * H_ * T_ * N_ * 64; // 25165824
    u16* pre = spk + (size_t)TOTAL_SPK_;            // 3145728
    unsigned int* cnt = (unsigned int*)(pre + (size_t)B_ * T_ * N_ * D_);
    // total ~87 MB

    cast_all      <<<dim3((B_*T_*N_*D_/4 + 255) / 256, 5), 256, 0, stream>>>(
                      x, wq, wk, wv, wo, xb, wqb, wkb, wvb, wob);
    proj_mfma     <<<dim3(32, 6, 3), 256, 0, stream>>>(xb, wqb, wkb, wvb, q, k, vT);
    score_lif_mfma<<<dim3(4, 4, 24), 256, 0, stream>>>(q, k, spk, cnt);
    pv_mfma       <<<dim3(2, 1, 96), 256, 0, stream>>>(spk, vT, pre);
    wo_mfma       <<<dim3(32, 6), 256, 0, stream>>>(pre, wob, out);
    rate_kernel   <<<1, 256, 0, stream>>>(cnt, out + (size_t)B_ * T_ * N_ * D_);
}

// Round 4
// 162.078 us; speedup vs baseline: 9.5712x; 1.0519x over previous
//
#include <hip/hip_runtime.h>
#include <hip/hip_bf16.h>

// Problem constants
#define B_  2
#define T_  4
#define N_  512
#define D_  768
#define H_  12
#define DH_ 64
#define TOTAL_SPK_ (B_ * H_ * T_ * N_ * N_)  // 25165824
#define NBLK_SCORE_ 384                       // 4*4*24

typedef unsigned short u16;
typedef __attribute__((ext_vector_type(8))) __bf16 bf16x8;
typedef __attribute__((ext_vector_type(4))) float f32x4;
typedef __attribute__((ext_vector_type(4))) u16 u16x4;
typedef __attribute__((ext_vector_type(8))) u16 u16x8;
typedef __attribute__((address_space(1))) const unsigned int glds_src;
typedef __attribute__((address_space(3))) unsigned int glds_dst;

__device__ __forceinline__ u16 f2bf(float f) {
    unsigned int u = __builtin_bit_cast(unsigned int, f);
    u += 0x7fffu + ((u >> 16) & 1u);          // RNE
    return (u16)(u >> 16);
}

// ---------------------------------------------------------------------------
// Stage nrows rows (multiple of 8; lrow0 multiple of 8) of a [*][64]-bf16 LDS
// tile (128 B rows) from row-major global (stride gld elems, k0 elem offset).
// global_load_lds writes linearly (wave base + lane*16); the XOR swizzle
// (byte ^= (row&7)<<4) is applied by PRE-SWIZZLING the per-lane global source
// column (rule #21: linear dest + inverse-swz source + swz on read).
// ---------------------------------------------------------------------------
__device__ __forceinline__ void stage64(u16* lds, const u16* g, int gld,
                                        int lrow0, int nrows, int grow0, int k0, int lane)
{
    const int sub = lane >> 3;                              // row within 8-row instr
    const int csrc = (((lane & 7) ^ sub) << 4);             // pre-swizzled src byte col
    #pragma unroll
    for (int j = 0; j < nrows; j += 8) {
        const u16* src = g + (size_t)(grow0 + j + sub) * gld + k0 + (csrc >> 1);
        __builtin_amdgcn_global_load_lds((glds_src*)src,
                                         (glds_dst*)(lds + (lrow0 + j) * 64),
                                         16, 0, 0);
    }
}

// Read one 16x32 A/B fragment (8 bf16/lane) from a swizzled [*][64] tile.
__device__ __forceinline__ bf16x8 ldfrag(const u16* lds, int rowbase, int kelem, int lane)
{
    const int r = rowbase + (lane & 15);
    const int cb = (((kelem + ((lane >> 4) << 3)) << 1)) ^ ((r & 7) << 4);
    return *reinterpret_cast<const bf16x8*>(
        reinterpret_cast<const char*>(lds) + (size_t)r * 128 + cb);
}

#define MFMA(a, b, c) __builtin_amdgcn_mfma_f32_16x16x32_bf16((a), (b), (c), 0, 0, 0)

// ---------------------------------------------------------------------------
// Kernel 0: cast fp32 -> bf16 (x and the four weight matrices)
// ---------------------------------------------------------------------------
__global__ __launch_bounds__(256) void cast_all(
    const float* __restrict__ x,  const float* __restrict__ wq, const float* __restrict__ wk,
    const float* __restrict__ wv, const float* __restrict__ wo,
    u16* __restrict__ xb, u16* __restrict__ wqb, u16* __restrict__ wkb,
    u16* __restrict__ wvb, u16* __restrict__ wob)
{
    const int z = blockIdx.y;
    const float* s; u16* d; int n4;
    switch (z) {
        case 0: s = x;  d = xb;  n4 = (B_*T_*N_*D_) / 4; break;   // 786432
        case 1: s = wq; d = wqb; n4 = (D_*D_) / 4; break;         // 147456
        case 2: s = wk; d = wkb; n4 = (D_*D_) / 4; break;
        case 3: s = wv; d = wvb; n4 = (D_*D_) / 4; break;
        default: s = wo; d = wob; n4 = (D_*D_) / 4; break;
    }
    const int i = blockIdx.x * 256 + threadIdx.x;
    if (i < n4) {
        float4 v = reinterpret_cast<const float4*>(s)[i];
        u16x4 o = { f2bf(v.x), f2bf(v.y), f2bf(v.z), f2bf(v.w) };
        reinterpret_cast<u16x4*>(d)[i] = o;
    }
}

// ---------------------------------------------------------------------------
// Kernel 1: QKV projection, bf16 MFMA NT-GEMM with 2-phase LDS double-buffer.
// y = x @ W^T, M=4096 N=768 K=768.  z picks weight. q,k stored [bh][t][n][64];
// v stored TRANSPOSED vT[bh][t][dh][n].
// ---------------------------------------------------------------------------
__global__ __launch_bounds__(256) void proj_mfma(
    const u16* __restrict__ xb,
    const u16* __restrict__ wqb, const u16* __restrict__ wkb, const u16* __restrict__ wvb,
    u16* __restrict__ q, u16* __restrict__ k, u16* __restrict__ vT)
{
    const int z = blockIdx.z;
    const u16* __restrict__ w = (z == 0) ? wqb : (z == 1) ? wkb : wvb;
    const int m0 = blockIdx.x * 128;
    const int n0 = blockIdx.y * 128;
    __shared__ u16 As[2][128 * 64];
    __shared__ u16 Bs[2][128 * 64];
    const int tid = threadIdx.x, lane = tid & 63, wid = tid >> 6;
    const int wr = wid >> 1, wc = wid & 1;

    f32x4 acc[4][4];
    #pragma unroll
    for (int i = 0; i < 4; ++i)
        #pragma unroll
        for (int j = 0; j < 4; ++j) acc[i][j] = f32x4{0.f, 0.f, 0.f, 0.f};

    // prologue: stage K-tile 0
    stage64(As[0], xb, D_, wid * 32, 32, m0 + wid * 32, 0, lane);
    stage64(Bs[0], w,  D_, wid * 32, 32, n0 + wid * 32, 0, lane);
    __syncthreads();

    const int NK = D_ / 64;                 // 12
    for (int kt = 0; kt < NK; ++kt) {
        const int cur = kt & 1;
        if (kt + 1 < NK) {                  // prefetch next K-tile (wave-uniform branch)
            stage64(As[cur ^ 1], xb, D_, wid * 32, 32, m0 + wid * 32, (kt + 1) * 64, lane);
            stage64(Bs[cur ^ 1], w,  D_, wid * 32, 32, n0 + wid * 32, (kt + 1) * 64, lane);
            __builtin_amdgcn_sched_barrier(0);   // pin prefetch issue before ds_reads
        }
        bf16x8 af[4][2], bfr[4][2];
        #pragma unroll
        for (int mi = 0; mi < 4; ++mi) {
            af[mi][0] = ldfrag(As[cur], wr * 64 + mi * 16, 0, lane);
            af[mi][1] = ldfrag(As[cur], wr * 64 + mi * 16, 32, lane);
        }
        #pragma unroll
        for (int ni = 0; ni < 4; ++ni) {
            bfr[ni][0] = ldfrag(Bs[cur], wc * 64 + ni * 16, 0, lane);
            bfr[ni][1] = ldfrag(Bs[cur], wc * 64 + ni * 16, 32, lane);
        }
        #pragma unroll
        for (int kk = 0; kk < 2; ++kk)
            #pragma unroll
            for (int mi = 0; mi < 4; ++mi)
                #pragma unroll
                for (int ni = 0; ni < 4; ++ni)
                    acc[mi][ni] = MFMA(af[mi][kk], bfr[ni][kk], acc[mi][ni]);
        __syncthreads();                    // drains prefetch (vmcnt0) + protects LDS reuse
    }

    // C/D layout: col = lane&15, row = (lane>>4)*4 + reg   [m89/m91 verified]
    if (z < 2) {
        u16* __restrict__ dst = (z == 0) ? q : k;
        #pragma unroll
        for (int mi = 0; mi < 4; ++mi)
            #pragma unroll
            for (int ni = 0; ni < 4; ++ni) {
                const int col = n0 + wc * 64 + ni * 16 + (lane & 15);
                const int h = col >> 6, dh = col & 63;
                const int row0 = m0 + wr * 64 + mi * 16 + ((lane >> 4) << 2);
                const int b = row0 >> 11, t = (row0 >> 9) & 3, n = row0 & 511;
                u16* p = dst + (size_t)(((b * H_ + h) * T_ + t) * N_ + n) * 64 + dh;
                f32x4 a = acc[mi][ni];
                p[0] = f2bf(a[0]); p[64] = f2bf(a[1]); p[128] = f2bf(a[2]); p[192] = f2bf(a[3]);
            }
    } else {
        #pragma unroll
        for (int mi = 0; mi < 4; ++mi)
            #pragma unroll
            for (int ni = 0; ni < 4; ++ni) {
                const int col = n0 + wc * 64 + ni * 16 + (lane & 15);
                const int h = col >> 6, dh = col & 63;
                const int row0 = m0 + wr * 64 + mi * 16 + ((lane >> 4) << 2);
                const int b = row0 >> 11, t = (row0 >> 9) & 3, n = row0 & 511;
                f32x4 a = acc[mi][ni];
                u16x4 o = { f2bf(a[0]), f2bf(a[1]), f2bf(a[2]), f2bf(a[3]) };
                *reinterpret_cast<u16x4*>(
                    vT + (size_t)(((b * H_ + h) * T_ + t) * 64 + dh) * N_ + n) = o;
            }
    }
}

// ---------------------------------------------------------------------------
// Kernel 2: fused scores + LIF, bf16 MFMA.  UNCHANGED from R3 (runs at ~5
// blocks/CU with 32 KB shared LDS; dbuf would cost the occupancy that hides
// its latency). Numerics frozen.
// ---------------------------------------------------------------------------
__global__ __launch_bounds__(256) void score_lif_mfma(
    const u16* __restrict__ q, const u16* __restrict__ k,
    u16* __restrict__ spk, unsigned int* __restrict__ cnt)
{
    const int bh = blockIdx.z;
    const int n0 = blockIdx.x * 128;    // query rows
    const int mb0 = blockIdx.y * 128;   // key cols
    __shared__ u16 SM[128 * 128];       // 32 KB: staging (As|Bs) then spike tile
    u16* As = SM;
    u16* Bs = SM + 8192;
    __shared__ int red4[4];
    const int tid = threadIdx.x, lane = tid & 63, wid = tid >> 6;
    const int wr = wid >> 1, wc = wid & 1;

    const float beta = 0.95122942450071400f;  // exp(-1/20)
    f32x4 mem[4][4];
    #pragma unroll
    for (int i = 0; i < 4; ++i)
        #pragma unroll
        for (int j = 0; j < 4; ++j) mem[i][j] = f32x4{0.f, 0.f, 0.f, 0.f};
    int c = 0;

    for (int t = 0; t < T_; ++t) {
        const u16* qs = q + (size_t)(bh * T_ + t) * (N_ * 64);
        const u16* ks = k + (size_t)(bh * T_ + t) * (N_ * 64);
        __syncthreads();
        stage64(As, qs, 64, wid * 32, 32, n0 + wid * 32, 0, lane);
        stage64(Bs, ks, 64, wid * 32, 32, mb0 + wid * 32, 0, lane);
        __syncthreads();

        f32x4 acc[4][4];
        #pragma unroll
        for (int i = 0; i < 4; ++i)
            #pragma unroll
            for (int j = 0; j < 4; ++j) acc[i][j] = f32x4{0.f, 0.f, 0.f, 0.f};
        bf16x8 af[4][2], bfr[4][2];
        #pragma unroll
        for (int mi = 0; mi < 4; ++mi) {
            af[mi][0] = ldfrag(As, wr * 64 + mi * 16, 0, lane);
            af[mi][1] = ldfrag(As, wr * 64 + mi * 16, 32, lane);
        }
        #pragma unroll
        for (int ni = 0; ni < 4; ++ni) {
            bfr[ni][0] = ldfrag(Bs, wc * 64 + ni * 16, 0, lane);
            bfr[ni][1] = ldfrag(Bs, wc * 64 + ni * 16, 32, lane);
        }
        #pragma unroll
        for (int kk = 0; kk < 2; ++kk)
            #pragma unroll
            for (int mi = 0; mi < 4; ++mi)
                #pragma unroll
                for (int ni = 0; ni < 4; ++ni)
                    acc[mi][ni] = MFMA(af[mi][kk], bfr[ni][kk], acc[mi][ni]);

        __syncthreads();   // all LDS reads done before spike tile overwrites SM

        // LIF update (registers) + spike tile into LDS as bf16
        #pragma unroll
        for (int mi = 0; mi < 4; ++mi)
            #pragma unroll
            for (int ni = 0; ni < 4; ++ni) {
                const int lcol = wc * 64 + ni * 16 + (lane & 15);
                const int lrow0 = wr * 64 + mi * 16 + ((lane >> 4) << 2);
                f32x4 a = acc[mi][ni];
                #pragma unroll
                for (int r = 0; r < 4; ++r) {
                    float mm = beta * mem[mi][ni][r] + a[r] * 0.125f;
                    const bool sp = (mm >= 0.5f);
                    mem[mi][ni][r] = mm - (sp ? 0.5f : 0.0f);
                    SM[(lrow0 + r) * 128 + lcol] = sp ? (u16)0x3F80u : (u16)0u;
                    c += sp ? 1 : 0;
                }
            }
        __syncthreads();

        // coalesced copy-out: 16 lanes cover one 256 B row segment
        u16* gb = spk + ((size_t)(bh * T_ + t) << 18) + (size_t)n0 * N_ + mb0;
        #pragma unroll
        for (int p = 0; p < 8; ++p) {
            const int row = p * 16 + (tid >> 4);
            const int cc = (tid & 15) * 8;
            *reinterpret_cast<u16x8*>(gb + (size_t)row * N_ + cc) =
                *reinterpret_cast<const u16x8*>(SM + row * 128 + cc);
        }
    }

    #pragma unroll
    for (int off = 32; off > 0; off >>= 1) c += __shfl_down(c, off);
    if ((tid & 63) == 0) red4[tid >> 6] = c;
    __syncthreads();
    if (tid == 0)
        cnt[(blockIdx.z * 4 + blockIdx.y) * 4 + blockIdx.x] =
            (unsigned int)(red4[0] + red4[1] + red4[2] + red4[3]);
}

// ---------------------------------------------------------------------------
// Kernel 3: PV, bf16 MFMA NT-GEMM, 2-phase double-buffer.  pre = spk @ v.
// A = spk[n][m] (K=m=512), B = vT[dh][m].  Tile 256x64. Output bf16 [b,t,n][D].
// ---------------------------------------------------------------------------
__global__ __launch_bounds__(256) void pv_mfma(
    const u16* __restrict__ spk, const u16* __restrict__ vT, u16* __restrict__ pre)
{
    const int batch = blockIdx.z;                 // bh*4 + t
    const int m0 = blockIdx.x * 256;              // n rows
    const u16* A  = spk + ((size_t)batch << 18);
    const u16* Bv = vT + (size_t)batch * (64 * N_);
    __shared__ u16 As[2][256 * 64];   // 2 x 32 KB
    __shared__ u16 Bs[2][64 * 64];    // 2 x 8 KB
    const int tid = threadIdx.x, lane = tid & 63, wid = tid >> 6;

    f32x4 acc[4][4];
    #pragma unroll
    for (int i = 0; i < 4; ++i)
        #pragma unroll
        for (int j = 0; j < 4; ++j) acc[i][j] = f32x4{0.f, 0.f, 0.f, 0.f};

    stage64(As[0], A,  N_, wid * 64, 64, m0 + wid * 64, 0, lane);
    stage64(Bs[0], Bv, N_, wid * 16, 16, wid * 16,      0, lane);
    __syncthreads();

    const int NK = N_ / 64;                 // 8
    for (int kt = 0; kt < NK; ++kt) {
        const int cur = kt & 1;
        if (kt + 1 < NK) {
            stage64(As[cur ^ 1], A,  N_, wid * 64, 64, m0 + wid * 64, (kt + 1) * 64, lane);
            stage64(Bs[cur ^ 1], Bv, N_, wid * 16, 16, wid * 16,      (kt + 1) * 64, lane);
            __builtin_amdgcn_sched_barrier(0);
        }
        bf16x8 af[4][2], bfr[4][2];
        #pragma unroll
        for (int mi = 0; mi < 4; ++mi) {
            af[mi][0] = ldfrag(As[cur], wid * 64 + mi * 16, 0, lane);
            af[mi][1] = ldfrag(As[cur], wid * 64 + mi * 16, 32, lane);
        }
        #pragma unroll
        for (int ni = 0; ni < 4; ++ni) {
            bfr[ni][0] = ldfrag(Bs[cur], ni * 16, 0, lane);
            bfr[ni][1] = ldfrag(Bs[cur], ni * 16, 32, lane);
        }
        #pragma unroll
        for (int kk = 0; kk < 2; ++kk)
            #pragma unroll
            for (int mi = 0; mi < 4; ++mi)
                #pragma unroll
                for (int ni = 0; ni < 4; ++ni)
                    acc[mi][ni] = MFMA(af[mi][kk], bfr[ni][kk], acc[mi][ni]);
        __syncthreads();
    }

    const int bh = batch >> 2, t = batch & 3;
    const int b = bh / H_, h = bh % H_;
    #pragma unroll
    for (int mi = 0; mi < 4; ++mi)
        #pragma unroll
        for (int ni = 0; ni < 4; ++ni) {
            const int dh = ni * 16 + (lane & 15);
            const int n = m0 + wid * 64 + mi * 16 + ((lane >> 4) << 2);
            f32x4 a = acc[mi][ni];
            u16* p = pre + (size_t)((b * T_ + t) * N_ + n) * D_ + h * 64 + dh;
            p[0] = f2bf(a[0]); p[D_] = f2bf(a[1]); p[2 * D_] = f2bf(a[2]); p[3 * D_] = f2bf(a[3]);
        }
}

// ---------------------------------------------------------------------------
// Kernel 4: output projection, bf16 MFMA NT-GEMM, 2-phase double-buffer.
// out = pre @ wo^T (fp32 out)
// ---------------------------------------------------------------------------
__global__ __launch_bounds__(256) void wo_mfma(
    const u16* __restrict__ pre, const u16* __restrict__ wob, float* __restrict__ out)
{
    const int m0 = blockIdx.x * 128;
    const int n0 = blockIdx.y * 128;
    __shared__ u16 As[2][128 * 64];
    __shared__ u16 Bs[2][128 * 64];
    const int tid = threadIdx.x, lane = tid & 63, wid = tid >> 6;
    const int wr = wid >> 1, wc = wid & 1;

    f32x4 acc[4][4];
    #pragma unroll
    for (int i = 0; i < 4; ++i)
        #pragma unroll
        for (int j = 0; j < 4; ++j) acc[i][j] = f32x4{0.f, 0.f, 0.f, 0.f};

    stage64(As[0], pre, D_, wid * 32, 32, m0 + wid * 32, 0, lane);
    stage64(Bs[0], wob, D_, wid * 32, 32, n0 + wid * 32, 0, lane);
    __syncthreads();

    const int NK = D_ / 64;                 // 12
    for (int kt = 0; kt < NK; ++kt) {
        const int cur = kt & 1;
        if (kt + 1 < NK) {
            stage64(As[cur ^ 1], pre, D_, wid * 32, 32, m0 + wid * 32, (kt + 1) * 64, lane);
            stage64(Bs[cur ^ 1], wob, D_, wid * 32, 32, n0 + wid * 32, (kt + 1) * 64, lane);
            __builtin_amdgcn_sched_barrier(0);
        }
        bf16x8 af[4][2], bfr[4][2];
        #pragma unroll
        for (int mi = 0; mi < 4; ++mi) {
            af[mi][0] = ldfrag(As[cur], wr * 64 + mi * 16, 0, lane);
            af[mi][1] = ldfrag(As[cur], wr * 64 + mi * 16, 32, lane);
        }
        #pragma unroll
        for (int ni = 0; ni < 4; ++ni) {
            bfr[ni][0] = ldfrag(Bs[cur], wc * 64 + ni * 16, 0, lane);
            bfr[ni][1] = ldfrag(Bs[cur], wc * 64 + ni * 16, 32, lane);
        }
        #pragma unroll
        for (int kk = 0; kk < 2; ++kk)
            #pragma unroll
            for (int mi = 0; mi < 4; ++mi)
                #pragma unroll
                for (int ni = 0; ni < 4; ++ni)
                    acc[mi][ni] = MFMA(af[mi][kk], bfr[ni][kk], acc[mi][ni]);
        __syncthreads();
    }

    #pragma unroll
    for (int mi = 0; mi < 4; ++mi)
        #pragma unroll
        for (int ni = 0; ni < 4; ++ni) {
            const int col = n0 + wc * 64 + ni * 16 + (lane & 15);
            const int row0 = m0 + wr * 64 + mi * 16 + ((lane >> 4) << 2);
            f32x4 a = acc[mi][ni];
            float* p = out + (size_t)row0 * D_ + col;
            p[0] = a[0]; p[D_] = a[1]; p[2 * D_] = a[2]; p[3 * D_] = a[3];
        }
}

// ---------------------------------------------------------------------------
// Kernel 5: attn_rate = sum(per-block counts) / 25165824   (no atomics)
// ---------------------------------------------------------------------------
__global__ __launch_bounds__(256) void rate_kernel(
    const unsigned int* __restrict__ cnt, float* __restrict__ out)
{
    __shared__ unsigned int red4[4];
    const int tid = threadIdx.x;
    unsigned int c = 0;
    for (int i = tid; i < NBLK_SCORE_; i += 256) c += cnt[i];
    #pragma unroll
    for (int off = 32; off > 0; off >>= 1) c += __shfl_down(c, off);
    if ((tid & 63) == 0) red4[tid >> 6] = c;
    __syncthreads();
    if (tid == 0) {
        double total = (double)red4[0] + red4[1] + red4[2] + red4[3];
        out[0] = (float)(total / (double)TOTAL_SPK_);
    }
}

// ---------------------------------------------------------------------------
extern "C" void kernel_launch(void* const* d_in, const int* in_sizes, int n_in,
                              void* d_out, int out_size, void* d_ws, size_t ws_size,
                              hipStream_t stream)
{
    const float* x  = (const float*)d_in[0];
    const float* wq = (const float*)d_in[1];
    const float* wk = (const float*)d_in[2];
    const float* wv = (const float*)d_in[3];
    const float* wo = (const float*)d_in[4];
    float* out = (float*)d_out;

    // workspace (u16 units): xb | wqb wkb wvb wob | q k vT | spk | pre | cnt
    u16* xb  = (u16*)d_ws;                          // 3145728
    u16* wqb = xb + (size_t)B_ * T_ * N_ * D_;      // 589824 each
    u16* wkb = wqb + D_ * D_;
    u16* wvb = wkb + D_ * D_;
    u16* wob = wvb + D_ * D_;
    u16* q   = wob + D_ * D_;                       // 3145728 each
    u16* k   = q + (size_t)B_ * H_ * T_ * N_ * 64;
    u16* vT  = k + (size_t)B_ * H_ * T_ * N_ * 64;
    u16* spk = vT + (size_t)B_ * H_ * T_ * N_ * 64; // 25165824
    u16* pre = spk + (size_t)TOTAL_SPK_;            // 3145728
    unsigned int* cnt = (unsigned int*)(pre + (size_t)B_ * T_ * N_ * D_);
    // total ~87 MB

    cast_all      <<<dim3((B_*T_*N_*D_/4 + 255) / 256, 5), 256, 0, stream>>>(
                      x, wq, wk, wv, wo, xb, wqb, wkb, wvb, wob);
    proj_mfma     <<<dim3(32, 6, 3), 256, 0, stream>>>(xb, wqb, wkb, wvb, q, k, vT);
    score_lif_mfma<<<dim3(4, 4, 24), 256, 0, stream>>>(q, k, spk, cnt);
    pv_mfma       <<<dim3(2, 1, 96), 256, 0, stream>>>(spk, vT, pre);
    wo_mfma       <<<dim3(32, 6), 256, 0, stream>>>(pre, wob, out);
    rate_kernel   <<<1, 256, 0, stream>>>(cnt, out + (size_t)B_ * T_ * N_ * D_);
}